// Round 1
// 11945.402 us; speedup vs baseline: 1.1897x; 1.1897x over previous
//
#include <hip/hip_runtime.h>

using bf16x8 = __attribute__((ext_vector_type(8))) __bf16;
using f32x4  = __attribute__((ext_vector_type(4))) float;
typedef unsigned short ushort_t;

constexpr int NB = 2048;   // batch
constexpr int NT = 256;    // timesteps
constexpr int NP = 5;      // stroke dim
constexpr int NZ = 128;    // latent dim
constexpr int NH = 1024;   // hidden
constexpr int NK = 20;     // mixture components
constexpr int NO = 123;    // 6*NK+3
constexpr int TO_ = NT * NO;

// workspace layout (bytes) — ~27.1 MiB total
constexpr size_t HBUF_OFF = 0;                        // 2 * 2048*1024 bf16 = 8 MiB (h ping-pong)
constexpr size_t WHH_OFF  = 8ull  * 1024 * 1024;      // 4096*1024 bf16 = 8 MiB
constexpr size_t WZ_OFF   = 16ull * 1024 * 1024;      // 4096*128 bf16 = 1 MiB (w_ih z-cols)
constexpr size_t WDEC_OFF = 17ull * 1024 * 1024;      // 123*1024 bf16 = 246 KiB
constexpr size_t ZBF_OFF  = 17ull * 1024 * 1024 + 512 * 1024;  // 2048*128 bf16 = 512 KiB
constexpr size_t YWS_OFF  = 18ull * 1024 * 1024;      // 2048*128 f32 = 1 MiB
constexpr size_t CWS_OFF  = 19ull * 1024 * 1024;      // 2048*1024 f32 = 8 MiB (cell state)
constexpr size_t QK_OFF   = 27ull * 1024 * 1024;      // 256 f32

__device__ __forceinline__ ushort_t f2bfr(float f) {
  unsigned int v; __builtin_memcpy(&v, &f, 4);
  v += 0x7fffu + ((v >> 16) & 1u);          // round-to-nearest-even
  return (ushort_t)(v >> 16);
}
__device__ __forceinline__ float sigm(float x) { return 1.f / (1.f + __expf(-x)); }
__device__ __forceinline__ float tanh_(float x) {
  x = fminf(fmaxf(x, -30.f), 30.f);
  float e = __expf(2.f * x);
  return (e - 1.f) / (e + 1.f);
}
__device__ __forceinline__ float wredmax(float v) {
  #pragma unroll
  for (int m = 32; m; m >>= 1) v = fmaxf(v, __shfl_xor(v, m, 64));
  return v;
}
__device__ __forceinline__ float wredsum(float v) {
  #pragma unroll
  for (int m = 32; m; m >>= 1) v += __shfl_xor(v, m, 64);
  return v;
}

// async global->LDS, 16 B per lane; LDS dest is wave-uniform base + lane*16
__device__ __forceinline__ void gload16(const void* g, void* l) {
  __builtin_amdgcn_global_load_lds(
      (const __attribute__((address_space(1))) void*)g,
      (__attribute__((address_space(3))) void*)l, 16, 0, 0);
}

// per-row output transform: softmax(pi), means, exp(std), tanh(cor), qk/qk_sum
__device__ __forceinline__ void do_transform(const float* __restrict__ yrow, float qkt,
                                             float* __restrict__ outp, int lane) {
  float pv = (lane < NK) ? yrow[lane * 6] : -3.0e38f;
  float mx = wredmax(pv);
  float ev = (lane < NK) ? __expf(pv - mx) : 0.f;
  float sm = wredsum(ev);
  if (lane < NK) {
    outp[lane]          = ev / sm;
    outp[NK + lane]     = yrow[lane * 6 + 1];
    outp[2 * NK + lane] = yrow[lane * 6 + 2];
    outp[3 * NK + lane] = __expf(fminf(yrow[lane * 6 + 3], 80.f));
    outp[4 * NK + lane] = __expf(fminf(yrow[lane * 6 + 4], 80.f));
    outp[5 * NK + lane] = tanh_(yrow[lane * 6 + 5]);
  }
  if (lane < 3)
    outp[6 * NK + lane] = __expf(fminf(yrow[120 + lane], 80.f)) / qkt;
}

// ---- once: convert f32 inputs to bf16 staging buffers
__global__ __launch_bounds__(512)
void prep_kernel(const float* __restrict__ whh, const float* __restrict__ wih,
                 const float* __restrict__ wdec, const float* __restrict__ zIn,
                 ushort_t* __restrict__ whh_bf, ushort_t* __restrict__ wz_bf,
                 ushort_t* __restrict__ wdec_bf, ushort_t* __restrict__ z_bf) {
  const int stride = 256 * 512;
  const int t0 = blockIdx.x * 512 + threadIdx.x;
  for (int i = t0; i < 4096 * 1024; i += stride) whh_bf[i] = f2bfr(whh[i]);
  for (int i = t0; i < 4096 * 128; i += stride) {
    int g = i >> 7, k = i & 127;
    wz_bf[i] = f2bfr(wih[(size_t)g * (NP + NZ) + NP + k]);
  }
  for (int i = t0; i < 123 * 1024; i += stride) wdec_bf[i] = f2bfr(wdec[i]);
  for (int i = t0; i < 2048 * 128;  i += stride) z_bf[i]  = f2bfr(zIn[i]);
}

// ---- once: h0 = tanh(z @ w_h0^T + b_h0) into hbuf slot 1 (f32 math)
__global__ __launch_bounds__(512)
void h0_kernel(const float* __restrict__ zIn, const float* __restrict__ wh0,
               const float* __restrict__ bh0, ushort_t* __restrict__ hout) {
  const int tid = threadIdx.x, blk = blockIdx.x;
  const int b0 = (blk >> 4) * 128, h0c = (blk & 15) * 64;
  const int m = tid >> 2, jg = tid & 3;
  const float* zr = zIn + (size_t)(b0 + m) * NZ;
  for (int j = jg * 16; j < jg * 16 + 16; ++j) {
    int hcol = h0c + j;
    float a = bh0[hcol];
    const float* wr = wh0 + (size_t)hcol * NZ;
    for (int q = 0; q < NZ; ++q) a += zr[q] * wr[q];
    hout[(size_t)(b0 + m) * NH + hcol] = f2bfr(tanh_(a));
  }
}

// ---- per step: [transforms for t-1] + gates GEMM + LSTM cell -> h(t)
// 128x128 tile (4 gate sections x 32 h-cols), 256 threads / 4 waves,
// grid 512 (16 b_grp x 32 h_grp) = 2 blocks/CU.
// global_load_lds direct staging into linear LDS with XOR chunk-swizzle
// (chunk ^= row&7), double-buffered, ONE barrier per K-tile.
__global__ __launch_bounds__(256, 2)
void stepA_kernel(int t,
                  const float* __restrict__ sIn, const ushort_t* __restrict__ z_bf,
                  const float* __restrict__ wih, const float* __restrict__ bih,
                  const float* __restrict__ bhh,
                  const ushort_t* __restrict__ whh_bf, const ushort_t* __restrict__ wz_bf,
                  const ushort_t* __restrict__ hin, ushort_t* __restrict__ hout,
                  float* __restrict__ cws, const float* __restrict__ yws,
                  const float* __restrict__ qks, float* __restrict__ out) {
  __shared__ __attribute__((aligned(16))) ushort_t aLds[2][128 * 64];
  __shared__ __attribute__((aligned(16))) ushort_t bLds[2][128 * 64];
  __shared__ float wPl[128 * NP];
  __shared__ float bl[128];
  __shared__ float sPl[128 * NP];

  const int tid = threadIdx.x, blk = blockIdx.x;
  const int wave = tid >> 6, lane = tid & 63;
  const int wm = wave & 1, wn = wave >> 1;          // 2 M-halves x 2 N-halves
  const int l15 = lane & 15, l4 = lane >> 4;
  const int b_grp = blk >> 5, h_grp = blk & 31;     // blk%8 = h_grp%8 -> whh slice L2-resident/XCD
  const int b0 = b_grp * 128, h0c = h_grp * 32;

  // phase 0: finalize step t-1 outputs (yws/qks complete across kernel boundary)
  if (t > 0) {
    int b = blk * 4 + wave;
    float qkt = __hip_atomic_load(&qks[t - 1], __ATOMIC_RELAXED, __HIP_MEMORY_SCOPE_AGENT);
    do_transform(yws + (size_t)b * 128, qkt,
                 out + (size_t)b * TO_ + (size_t)(t - 1) * NO, lane);
  }

  // stage per-block constants
  for (int idx = tid; idx < 128 * NP; idx += 256) {
    int rn = idx / NP, p = idx - rn * NP;
    int grow = (rn >> 5) * NH + h0c + (rn & 31);
    wPl[idx] = wih[(size_t)grow * (NP + NZ) + p];
  }
  if (tid < 128) {
    int grow = (tid >> 5) * NH + h0c + (tid & 31);
    bl[tid] = bih[grow] + bhh[grow];
  }
  for (int idx = tid; idx < 128 * NP; idx += 256) {
    int r = idx / NP, p = idx - r * NP;
    float v;
    if (t == 0) v = (p == 2) ? 1.f : 0.f;
    else        v = sIn[(size_t)(b0 + r) * (NT * NP) + (size_t)(t - 1) * NP + p];
    sPl[idx] = v;
  }

  // staging lane geometry: each 1 KiB chunk = 8 rows x 8 phys col-chunks of 16 B
  const int lr     = lane >> 3;        // row within chunk (== row&7)
  const int lclog  = (lane & 7) ^ lr;  // logical col-chunk for this phys slot (involution)

  auto stageA = [&](int buf, int kt) {
    #pragma unroll
    for (int j = 0; j < 4; ++j) {
      int ch = wave * 4 + j;           // 16 chunks cover 128 rows
      int r = ch * 8 + lr;
      const ushort_t* src = (kt < 16)
        ? &hin[(size_t)(b0 + r) * NH + kt * 64 + lclog * 8]
        : &z_bf[(size_t)(b0 + r) * NZ + (kt - 16) * 64 + lclog * 8];
      gload16(src, &aLds[buf][ch * 512]);
    }
  };
  auto stageB = [&](int buf, int kt) {
    #pragma unroll
    for (int j = 0; j < 4; ++j) {
      int ch = wave * 4 + j;
      int rn = ch * 8 + lr;
      int grow = (rn >> 5) * NH + h0c + (rn & 31);
      const ushort_t* src = (kt < 16)
        ? &whh_bf[(size_t)grow * NH + kt * 64 + lclog * 8]
        : &wz_bf[(size_t)grow * 128 + (kt - 16) * 64 + lclog * 8];
      gload16(src, &bLds[buf][ch * 512]);
    }
  };

  // gates GEMM: M=128 (batch) x N=128 (4 sections x 32 h-cols), K=1024(h)+128(z)
  f32x4 acc[4][4];
  #pragma unroll
  for (int mi = 0; mi < 4; ++mi)
    #pragma unroll
    for (int s = 0; s < 4; ++s) acc[mi][s] = f32x4{0.f, 0.f, 0.f, 0.f};

  stageA(0, 0); stageB(0, 0);
  __syncthreads();                     // drains vmcnt(0): buf0 ready

  for (int kt = 0; kt < 18; ++kt) {
    const int cur = kt & 1;
    if (kt < 17) { stageA(cur ^ 1, kt + 1); stageB(cur ^ 1, kt + 1); }  // in-flight over compute
    #pragma unroll
    for (int kk = 0; kk < 2; ++kk) {
      bf16x8 af[4], bfg[4];
      #pragma unroll
      for (int mi = 0; mi < 4; ++mi) {
        int r = wm * 64 + mi * 16 + l15;
        af[mi] = *(const bf16x8*)&aLds[cur][r * 64 + (((kk * 4 + l4) ^ (l15 & 7)) * 8)];
      }
      #pragma unroll
      for (int s = 0; s < 4; ++s) {
        int rn = s * 32 + wn * 16 + l15;
        bfg[s] = *(const bf16x8*)&bLds[cur][rn * 64 + (((kk * 4 + l4) ^ (l15 & 7)) * 8)];
      }
      #pragma unroll
      for (int mi = 0; mi < 4; ++mi)
        #pragma unroll
        for (int s = 0; s < 4; ++s)
          acc[mi][s] = __builtin_amdgcn_mfma_f32_16x16x32_bf16(af[mi], bfg[s], acc[mi][s], 0, 0, 0);
    }
    __syncthreads();                   // one barrier per K-tile: next buf ready, cur consumed
  }

  // LSTM cell: c in f32 global, h(t) out
  float wpv[4][NP];
  #pragma unroll
  for (int s = 0; s < 4; ++s) {
    int nl = s * 32 + wn * 16 + l15;
    #pragma unroll
    for (int p = 0; p < NP; ++p) wpv[s][p] = wPl[nl * NP + p];
  }
  const int colh = h0c + wn * 16 + l15;
  #pragma unroll
  for (int mi = 0; mi < 4; ++mi) {
    #pragma unroll
    for (int e = 0; e < 4; ++e) {
      int m = wm * 64 + mi * 16 + l4 * 4 + e;
      float sv0 = sPl[m * NP + 0], sv1 = sPl[m * NP + 1], sv2 = sPl[m * NP + 2];
      float sv3 = sPl[m * NP + 3], sv4 = sPl[m * NP + 4];
      float gv[4];
      #pragma unroll
      for (int s = 0; s < 4; ++s) {
        int nl = s * 32 + wn * 16 + l15;
        gv[s] = acc[mi][s][e] + bl[nl]
              + sv0 * wpv[s][0] + sv1 * wpv[s][1] + sv2 * wpv[s][2]
              + sv3 * wpv[s][3] + sv4 * wpv[s][4];
      }
      float ig = sigm(gv[0]);
      float fg = sigm(gv[1]);
      float gg = tanh_(gv[2]);
      float og = sigm(gv[3]);
      size_t ci = (size_t)(b0 + m) * NH + colh;
      float cn = fg * cws[ci] + ig * gg;
      cws[ci] = cn;
      hout[ci] = f2bfr(og * tanh_(cn));
    }
  }
}

// ---- per step: decoder y(t) = h(t) @ w_dec^T + b_dec, and qk exp-sum
// 256 blocks x 256 threads: (16-row tile) x (64-col half) per block -> 1 block/CU
__global__ __launch_bounds__(256)
void stepB_kernel(int t, const ushort_t* __restrict__ hcur,
                  const ushort_t* __restrict__ wdec_bf, const float* __restrict__ bdec,
                  float* __restrict__ yws, float* __restrict__ qks) {
  __shared__ __attribute__((aligned(16))) ushort_t hLds[16 * 1032];
  const int tid = threadIdx.x, blk = blockIdx.x;   // 256 blocks
  const int wave = tid >> 6, lane = tid & 63;
  const int l15 = lane & 15, l4 = lane >> 4;
  const int r0 = (blk >> 1) * 16;
  const int chalf = blk & 1;

  #pragma unroll
  for (int j = 0; j < 8; ++j) {
    int id = tid + 256 * j;            // 0..2047 chunks of 8
    int r = id >> 7, c = id & 127;
    *(uint4*)&hLds[r * 1032 + c * 8] = *(const uint4*)&hcur[(size_t)(r0 + r) * NH + c * 8];
  }
  __syncthreads();

  const int col = chalf * 64 + wave * 16 + l15;    // 0..127
  const int brow = col > 122 ? 122 : col;          // clamp; extra cols never read
  const ushort_t* ha = &hLds[l15 * 1032 + l4 * 8];
  const ushort_t* wb = wdec_bf + (size_t)brow * NH + l4 * 8;
  f32x4 dacc = {0.f, 0.f, 0.f, 0.f};
  #pragma unroll 4
  for (int k2 = 0; k2 < 32; ++k2) {
    bf16x8 a = *(const bf16x8*)(ha + k2 * 32);
    bf16x8 b = *(const bf16x8*)(wb + k2 * 32);
    dacc = __builtin_amdgcn_mfma_f32_16x16x32_bf16(a, b, dacc, 0, 0, 0);
  }
  float bd = (col < NO) ? bdec[col] : 0.f;
  #pragma unroll
  for (int e = 0; e < 4; ++e)
    yws[(size_t)(r0 + l4 * 4 + e) * 128 + col] = dacc[e] + bd;

  if (chalf == 1 && wave == 3) {                   // cols 112..127; qk = 120..122
    float qp = 0.f;
    if (l15 >= 8 && l15 <= 10) {
      #pragma unroll
      for (int e = 0; e < 4; ++e) qp += __expf(fminf(dacc[e] + bd, 80.f));
    }
    qp = wredsum(qp);
    if (lane == 0) atomicAdd(&qks[t], qp);
  }
}

// ---- once: transforms for the final step + mu/presig zeros
__global__ __launch_bounds__(512)
void finalC_kernel(const float* __restrict__ yws, const float* __restrict__ qks,
                   float* __restrict__ out) {
  const int tid = threadIdx.x, blk = blockIdx.x;
  const int wave = tid >> 6, lane = tid & 63;
  int b = blk * 8 + wave;
  float qkt = __hip_atomic_load(&qks[NT - 1], __ATOMIC_RELAXED, __HIP_MEMORY_SCOPE_AGENT);
  do_transform(yws + (size_t)b * 128, qkt,
               out + (size_t)b * TO_ + (size_t)(NT - 1) * NO, lane);
  if (blk == 0 && tid < 2 * NZ)
    out[(size_t)NB * TO_ + tid] = 0.f;   // mu, presig = zeros
}

extern "C" void kernel_launch(void* const* d_in, const int* in_sizes, int n_in,
                              void* d_out, int out_size, void* d_ws, size_t ws_size,
                              hipStream_t stream) {
  const float* sIn  = (const float*)d_in[0];
  const float* zIn  = (const float*)d_in[1];
  const float* wh0  = (const float*)d_in[2];
  const float* bh0  = (const float*)d_in[3];
  const float* wih  = (const float*)d_in[4];
  const float* bih  = (const float*)d_in[5];
  const float* whh  = (const float*)d_in[6];
  const float* bhh  = (const float*)d_in[7];
  const float* wdec = (const float*)d_in[8];
  const float* bdec = (const float*)d_in[9];
  float* out = (float*)d_out;
  char* ws = (char*)d_ws;
  ushort_t* hbuf    = (ushort_t*)(ws + HBUF_OFF);
  ushort_t* whh_bf  = (ushort_t*)(ws + WHH_OFF);
  ushort_t* wz_bf   = (ushort_t*)(ws + WZ_OFF);
  ushort_t* wdec_bf = (ushort_t*)(ws + WDEC_OFF);
  ushort_t* z_bf    = (ushort_t*)(ws + ZBF_OFF);
  float*    yws     = (float*)(ws + YWS_OFF);
  float*    cws     = (float*)(ws + CWS_OFF);
  float*    qks     = (float*)(ws + QK_OFF);

  hipMemsetAsync(cws, 0, (size_t)NB * NH * 4, stream);
  hipMemsetAsync(qks, 0, NT * 4, stream);
  prep_kernel<<<256, 512, 0, stream>>>(whh, wih, wdec, zIn, whh_bf, wz_bf, wdec_bf, z_bf);
  h0_kernel<<<256, 512, 0, stream>>>(zIn, wh0, bh0, hbuf + (size_t)NB * NH);

  for (int t = 0; t < NT; ++t) {
    const ushort_t* hin = hbuf + (size_t)((t + 1) & 1) * NB * NH;
    ushort_t*      hout = hbuf + (size_t)(t & 1) * NB * NH;
    stepA_kernel<<<512, 256, 0, stream>>>(t, sIn, z_bf, wih, bih, bhh, whh_bf, wz_bf,
                                          hin, hout, cws, yws, qks, out);
    stepB_kernel<<<256, 256, 0, stream>>>(t, hout, wdec_bf, bdec, yws, qks);
  }
  finalC_kernel<<<256, 512, 0, stream>>>(yws, qks, out);
}

// Round 2
// 10779.761 us; speedup vs baseline: 1.3184x; 1.1081x over previous
//
#include <hip/hip_runtime.h>

using bf16x8 = __attribute__((ext_vector_type(8))) __bf16;
using f32x4  = __attribute__((ext_vector_type(4))) float;
typedef unsigned short ushort_t;

constexpr int NB = 2048;   // batch
constexpr int NT = 256;    // timesteps
constexpr int NP = 5;      // stroke dim
constexpr int NZ = 128;    // latent dim
constexpr int NH = 1024;   // hidden
constexpr int NK = 20;     // mixture components
constexpr int NO = 123;    // 6*NK+3
constexpr int TO_ = NT * NO;

// workspace layout (bytes) — ~27.1 MiB total
constexpr size_t HBUF_OFF = 0;                        // 2 * 2048*1024 bf16 = 8 MiB (h ping-pong)
constexpr size_t WHH_OFF  = 8ull  * 1024 * 1024;      // 4096*1024 bf16 = 8 MiB
constexpr size_t WZ_OFF   = 16ull * 1024 * 1024;      // 4096*128 bf16 = 1 MiB (w_ih z-cols)
constexpr size_t WDEC_OFF = 17ull * 1024 * 1024;      // 123*1024 bf16 = 246 KiB
constexpr size_t ZBF_OFF  = 17ull * 1024 * 1024 + 512 * 1024;  // 2048*128 bf16 = 512 KiB
constexpr size_t YWS_OFF  = 18ull * 1024 * 1024;      // 2048*128 f32 = 1 MiB
constexpr size_t CWS_OFF  = 19ull * 1024 * 1024;      // 2048*1024 f32 = 8 MiB (cell state)
constexpr size_t QK_OFF   = 27ull * 1024 * 1024;      // 256 f32

__device__ __forceinline__ ushort_t f2bfr(float f) {
  unsigned int v; __builtin_memcpy(&v, &f, 4);
  v += 0x7fffu + ((v >> 16) & 1u);          // round-to-nearest-even
  return (ushort_t)(v >> 16);
}
__device__ __forceinline__ float sigm(float x) { return 1.f / (1.f + __expf(-x)); }
__device__ __forceinline__ float tanh_(float x) {
  x = fminf(fmaxf(x, -30.f), 30.f);
  float e = __expf(2.f * x);
  return (e - 1.f) / (e + 1.f);
}
__device__ __forceinline__ float wredmax(float v) {
  #pragma unroll
  for (int m = 32; m; m >>= 1) v = fmaxf(v, __shfl_xor(v, m, 64));
  return v;
}
__device__ __forceinline__ float wredsum(float v) {
  #pragma unroll
  for (int m = 32; m; m >>= 1) v += __shfl_xor(v, m, 64);
  return v;
}

// async global->LDS, 16 B per lane; LDS dest is wave-uniform base + lane*16
__device__ __forceinline__ void gload16(const void* g, void* l) {
  __builtin_amdgcn_global_load_lds(
      (const __attribute__((address_space(1))) void*)g,
      (__attribute__((address_space(3))) void*)l, 16, 0, 0);
}

// per-row output transform: softmax(pi), means, exp(std), tanh(cor), qk/qk_sum
__device__ __forceinline__ void do_transform(const float* __restrict__ yrow, float qkt,
                                             float* __restrict__ outp, int lane) {
  float pv = (lane < NK) ? yrow[lane * 6] : -3.0e38f;
  float mx = wredmax(pv);
  float ev = (lane < NK) ? __expf(pv - mx) : 0.f;
  float sm = wredsum(ev);
  if (lane < NK) {
    outp[lane]          = ev / sm;
    outp[NK + lane]     = yrow[lane * 6 + 1];
    outp[2 * NK + lane] = yrow[lane * 6 + 2];
    outp[3 * NK + lane] = __expf(fminf(yrow[lane * 6 + 3], 80.f));
    outp[4 * NK + lane] = __expf(fminf(yrow[lane * 6 + 4], 80.f));
    outp[5 * NK + lane] = tanh_(yrow[lane * 6 + 5]);
  }
  if (lane < 3)
    outp[6 * NK + lane] = __expf(fminf(yrow[120 + lane], 80.f)) / qkt;
}

// ---- once: convert f32 inputs to bf16 staging buffers
__global__ __launch_bounds__(512)
void prep_kernel(const float* __restrict__ whh, const float* __restrict__ wih,
                 const float* __restrict__ wdec, const float* __restrict__ zIn,
                 ushort_t* __restrict__ whh_bf, ushort_t* __restrict__ wz_bf,
                 ushort_t* __restrict__ wdec_bf, ushort_t* __restrict__ z_bf) {
  const int stride = 256 * 512;
  const int t0 = blockIdx.x * 512 + threadIdx.x;
  for (int i = t0; i < 4096 * 1024; i += stride) whh_bf[i] = f2bfr(whh[i]);
  for (int i = t0; i < 4096 * 128; i += stride) {
    int g = i >> 7, k = i & 127;
    wz_bf[i] = f2bfr(wih[(size_t)g * (NP + NZ) + NP + k]);
  }
  for (int i = t0; i < 123 * 1024; i += stride) wdec_bf[i] = f2bfr(wdec[i]);
  for (int i = t0; i < 2048 * 128;  i += stride) z_bf[i]  = f2bfr(zIn[i]);
}

// ---- once: h0 = tanh(z @ w_h0^T + b_h0) into hbuf slot 1 (f32 math)
__global__ __launch_bounds__(512)
void h0_kernel(const float* __restrict__ zIn, const float* __restrict__ wh0,
               const float* __restrict__ bh0, ushort_t* __restrict__ hout) {
  const int tid = threadIdx.x, blk = blockIdx.x;
  const int b0 = (blk >> 4) * 128, h0c = (blk & 15) * 64;
  const int m = tid >> 2, jg = tid & 3;
  const float* zr = zIn + (size_t)(b0 + m) * NZ;
  for (int j = jg * 16; j < jg * 16 + 16; ++j) {
    int hcol = h0c + j;
    float a = bh0[hcol];
    const float* wr = wh0 + (size_t)hcol * NZ;
    for (int q = 0; q < NZ; ++q) a += zr[q] * wr[q];
    hout[(size_t)(b0 + m) * NH + hcol] = f2bfr(tanh_(a));
  }
}

// ---- per step: [transforms for t-1] + gates GEMM + LSTM cell -> h(t)
// 128x128 tile, 256 threads / 4 waves, 2 blocks/CU.
// global_load_lds direct staging into linear LDS with XOR chunk-swizzle,
// double-buffered; T4 counted-vmcnt pipeline: per-wave s_waitcnt vmcnt(8)
// keeps next-tile loads in flight across raw s_barrier (no vmcnt(0) drain).
__global__ __launch_bounds__(256, 2)
void stepA_kernel(int t,
                  const float* __restrict__ sIn, const ushort_t* __restrict__ z_bf,
                  const float* __restrict__ wih, const float* __restrict__ bih,
                  const float* __restrict__ bhh,
                  const ushort_t* __restrict__ whh_bf, const ushort_t* __restrict__ wz_bf,
                  const ushort_t* __restrict__ hin, ushort_t* __restrict__ hout,
                  float* __restrict__ cws, const float* __restrict__ yws,
                  const float* __restrict__ qks, float* __restrict__ out) {
  __shared__ __attribute__((aligned(16))) ushort_t aLds[2][128 * 64];
  __shared__ __attribute__((aligned(16))) ushort_t bLds[2][128 * 64];
  __shared__ float wPl[128 * NP];
  __shared__ float bl[128];
  __shared__ float sPl[128 * NP];

  const int tid = threadIdx.x, blk = blockIdx.x;
  const int wave = tid >> 6, lane = tid & 63;
  const int wm = wave & 1, wn = wave >> 1;          // 2 M-halves x 2 N-halves
  const int l15 = lane & 15, l4 = lane >> 4;
  const int b_grp = blk >> 5, h_grp = blk & 31;     // blk%8 spreads h_grp across XCDs
  const int b0 = b_grp * 128, h0c = h_grp * 32;

  // staging lane geometry: each 1 KiB chunk = 8 rows x 8 phys col-chunks of 16 B
  const int lr     = lane >> 3;        // row within chunk (== row&7)
  const int lclog  = (lane & 7) ^ lr;  // logical col-chunk for this phys slot (involution)

  auto stageA = [&](int buf, int kt) {
    #pragma unroll
    for (int j = 0; j < 4; ++j) {
      int ch = wave * 4 + j;           // 16 chunks cover 128 rows
      int r = ch * 8 + lr;
      const ushort_t* src = (kt < 16)
        ? &hin[(size_t)(b0 + r) * NH + kt * 64 + lclog * 8]
        : &z_bf[(size_t)(b0 + r) * NZ + (kt - 16) * 64 + lclog * 8];
      gload16(src, &aLds[buf][ch * 512]);
    }
  };
  auto stageB = [&](int buf, int kt) {
    #pragma unroll
    for (int j = 0; j < 4; ++j) {
      int ch = wave * 4 + j;
      int rn = ch * 8 + lr;
      int grow = (rn >> 5) * NH + h0c + (rn & 31);
      const ushort_t* src = (kt < 16)
        ? &whh_bf[(size_t)grow * NH + kt * 64 + lclog * 8]
        : &wz_bf[(size_t)grow * 128 + (kt - 16) * 64 + lclog * 8];
      gload16(src, &bLds[buf][ch * 512]);
    }
  };

  // start tile-0 DMA before anything else
  stageA(0, 0); stageB(0, 0);

  // phase 0: finalize step t-1 outputs (overlaps tile-0 DMA)
  if (t > 0) {
    int b = blk * 4 + wave;
    float qkt = __hip_atomic_load(&qks[t - 1], __ATOMIC_RELAXED, __HIP_MEMORY_SCOPE_AGENT);
    do_transform(yws + (size_t)b * 128, qkt,
                 out + (size_t)b * TO_ + (size_t)(t - 1) * NO, lane);
  }

  // stage per-block constants
  for (int idx = tid; idx < 128 * NP; idx += 256) {
    int rn = idx / NP, p = idx - rn * NP;
    int grow = (rn >> 5) * NH + h0c + (rn & 31);
    wPl[idx] = wih[(size_t)grow * (NP + NZ) + p];
  }
  if (tid < 128) {
    int grow = (tid >> 5) * NH + h0c + (tid & 31);
    bl[tid] = bih[grow] + bhh[grow];
  }
  for (int idx = tid; idx < 128 * NP; idx += 256) {
    int r = idx / NP, p = idx - r * NP;
    float v;
    if (t == 0) v = (p == 2) ? 1.f : 0.f;
    else        v = sIn[(size_t)(b0 + r) * (NT * NP) + (size_t)(t - 1) * NP + p];
    sPl[idx] = v;
  }

  // gates GEMM: M=128 (batch) x N=128 (4 sections x 32 h-cols), K=1024(h)+128(z)
  f32x4 acc[4][4];
  #pragma unroll
  for (int mi = 0; mi < 4; ++mi)
    #pragma unroll
    for (int s = 0; s < 4; ++s) acc[mi][s] = f32x4{0.f, 0.f, 0.f, 0.f};

  __syncthreads();                     // full drain: buf0 + wPl/bl/sPl ready

  for (int kt = 0; kt < 18; ++kt) {
    const int cur = kt & 1;
    if (kt < 17) {
      stageA(cur ^ 1, kt + 1); stageB(cur ^ 1, kt + 1);   // 8 loads/wave, stay in flight
      asm volatile("s_waitcnt vmcnt(8)" ::: "memory");    // my 8 cur-tile loads done
    } else {
      asm volatile("s_waitcnt vmcnt(0)" ::: "memory");
    }
    __builtin_amdgcn_s_barrier();      // all waves' cur-tile loads done
    asm volatile("" ::: "memory");
    #pragma unroll
    for (int kk = 0; kk < 2; ++kk) {
      bf16x8 af[4], bfg[4];
      #pragma unroll
      for (int mi = 0; mi < 4; ++mi) {
        int r = wm * 64 + mi * 16 + l15;
        af[mi] = *(const bf16x8*)&aLds[cur][r * 64 + (((kk * 4 + l4) ^ (l15 & 7)) * 8)];
      }
      #pragma unroll
      for (int s = 0; s < 4; ++s) {
        int rn = s * 32 + wn * 16 + l15;
        bfg[s] = *(const bf16x8*)&bLds[cur][rn * 64 + (((kk * 4 + l4) ^ (l15 & 7)) * 8)];
      }
      __builtin_amdgcn_s_setprio(1);
      #pragma unroll
      for (int mi = 0; mi < 4; ++mi)
        #pragma unroll
        for (int s = 0; s < 4; ++s)
          acc[mi][s] = __builtin_amdgcn_mfma_f32_16x16x32_bf16(af[mi], bfg[s], acc[mi][s], 0, 0, 0);
      __builtin_amdgcn_s_setprio(0);
    }
    asm volatile("" ::: "memory");
    __builtin_amdgcn_s_barrier();      // cur buffer fully consumed before reuse
    asm volatile("" ::: "memory");
  }

  // LSTM cell: c in f32 global, h(t) out
  float wpv[4][NP];
  #pragma unroll
  for (int s = 0; s < 4; ++s) {
    int nl = s * 32 + wn * 16 + l15;
    #pragma unroll
    for (int p = 0; p < NP; ++p) wpv[s][p] = wPl[nl * NP + p];
  }
  const int colh = h0c + wn * 16 + l15;
  #pragma unroll
  for (int mi = 0; mi < 4; ++mi) {
    #pragma unroll
    for (int e = 0; e < 4; ++e) {
      int m = wm * 64 + mi * 16 + l4 * 4 + e;
      float sv0 = sPl[m * NP + 0], sv1 = sPl[m * NP + 1], sv2 = sPl[m * NP + 2];
      float sv3 = sPl[m * NP + 3], sv4 = sPl[m * NP + 4];
      float gv[4];
      #pragma unroll
      for (int s = 0; s < 4; ++s) {
        int nl = s * 32 + wn * 16 + l15;
        gv[s] = acc[mi][s][e] + bl[nl]
              + sv0 * wpv[s][0] + sv1 * wpv[s][1] + sv2 * wpv[s][2]
              + sv3 * wpv[s][3] + sv4 * wpv[s][4];
      }
      float ig = sigm(gv[0]);
      float fg = sigm(gv[1]);
      float gg = tanh_(gv[2]);
      float og = sigm(gv[3]);
      size_t ci = (size_t)(b0 + m) * NH + colh;
      float cn = fg * cws[ci] + ig * gg;
      cws[ci] = cn;
      hout[ci] = f2bfr(og * tanh_(cn));
    }
  }
}

// ---- per step: decoder y(t) = h(t) @ w_dec^T + b_dec, and qk exp-sum
// 256 blocks x 256 threads: (16-row tile) x (64-col half) per block
__global__ __launch_bounds__(256)
void stepB_kernel(int t, const ushort_t* __restrict__ hcur,
                  const ushort_t* __restrict__ wdec_bf, const float* __restrict__ bdec,
                  float* __restrict__ yws, float* __restrict__ qks) {
  __shared__ __attribute__((aligned(16))) ushort_t hLds[16 * 1032];
  const int tid = threadIdx.x, blk = blockIdx.x;   // 256 blocks
  const int wave = tid >> 6, lane = tid & 63;
  const int l15 = lane & 15, l4 = lane >> 4;
  const int r0 = (blk >> 1) * 16;
  const int chalf = blk & 1;

  #pragma unroll
  for (int j = 0; j < 8; ++j) {
    int id = tid + 256 * j;            // 0..2047 chunks of 8
    int r = id >> 7, c = id & 127;
    *(uint4*)&hLds[r * 1032 + c * 8] = *(const uint4*)&hcur[(size_t)(r0 + r) * NH + c * 8];
  }
  __syncthreads();

  const int col = chalf * 64 + wave * 16 + l15;    // 0..127
  const int brow = col > 122 ? 122 : col;          // clamp; extra cols never read
  const ushort_t* ha = &hLds[l15 * 1032 + l4 * 8];
  const ushort_t* wb = wdec_bf + (size_t)brow * NH + l4 * 8;
  f32x4 dacc = {0.f, 0.f, 0.f, 0.f};
  #pragma unroll 8
  for (int k2 = 0; k2 < 32; ++k2) {
    bf16x8 a = *(const bf16x8*)(ha + k2 * 32);
    bf16x8 b = *(const bf16x8*)(wb + k2 * 32);
    dacc = __builtin_amdgcn_mfma_f32_16x16x32_bf16(a, b, dacc, 0, 0, 0);
  }
  float bd = (col < NO) ? bdec[col] : 0.f;
  #pragma unroll
  for (int e = 0; e < 4; ++e)
    yws[(size_t)(r0 + l4 * 4 + e) * 128 + col] = dacc[e] + bd;

  if (chalf == 1 && wave == 3) {                   // cols 112..127; qk = 120..122
    float qp = 0.f;
    if (l15 >= 8 && l15 <= 10) {
      #pragma unroll
      for (int e = 0; e < 4; ++e) qp += __expf(fminf(dacc[e] + bd, 80.f));
    }
    qp = wredsum(qp);
    if (lane == 0) atomicAdd(&qks[t], qp);
  }
}

// ---- once: transforms for the final step + mu/presig zeros
__global__ __launch_bounds__(512)
void finalC_kernel(const float* __restrict__ yws, const float* __restrict__ qks,
                   float* __restrict__ out) {
  const int tid = threadIdx.x, blk = blockIdx.x;
  const int wave = tid >> 6, lane = tid & 63;
  int b = blk * 8 + wave;
  float qkt = __hip_atomic_load(&qks[NT - 1], __ATOMIC_RELAXED, __HIP_MEMORY_SCOPE_AGENT);
  do_transform(yws + (size_t)b * 128, qkt,
               out + (size_t)b * TO_ + (size_t)(NT - 1) * NO, lane);
  if (blk == 0 && tid < 2 * NZ)
    out[(size_t)NB * TO_ + tid] = 0.f;   // mu, presig = zeros
}

extern "C" void kernel_launch(void* const* d_in, const int* in_sizes, int n_in,
                              void* d_out, int out_size, void* d_ws, size_t ws_size,
                              hipStream_t stream) {
  const float* sIn  = (const float*)d_in[0];
  const float* zIn  = (const float*)d_in[1];
  const float* wh0  = (const float*)d_in[2];
  const float* bh0  = (const float*)d_in[3];
  const float* wih  = (const float*)d_in[4];
  const float* bih  = (const float*)d_in[5];
  const float* whh  = (const float*)d_in[6];
  const float* bhh  = (const float*)d_in[7];
  const float* wdec = (const float*)d_in[8];
  const float* bdec = (const float*)d_in[9];
  float* out = (float*)d_out;
  char* ws = (char*)d_ws;
  ushort_t* hbuf    = (ushort_t*)(ws + HBUF_OFF);
  ushort_t* whh_bf  = (ushort_t*)(ws + WHH_OFF);
  ushort_t* wz_bf   = (ushort_t*)(ws + WZ_OFF);
  ushort_t* wdec_bf = (ushort_t*)(ws + WDEC_OFF);
  ushort_t* z_bf    = (ushort_t*)(ws + ZBF_OFF);
  float*    yws     = (float*)(ws + YWS_OFF);
  float*    cws     = (float*)(ws + CWS_OFF);
  float*    qks     = (float*)(ws + QK_OFF);

  hipMemsetAsync(cws, 0, (size_t)NB * NH * 4, stream);
  hipMemsetAsync(qks, 0, NT * 4, stream);
  prep_kernel<<<256, 512, 0, stream>>>(whh, wih, wdec, zIn, whh_bf, wz_bf, wdec_bf, z_bf);
  h0_kernel<<<256, 512, 0, stream>>>(zIn, wh0, bh0, hbuf + (size_t)NB * NH);

  for (int t = 0; t < NT; ++t) {
    const ushort_t* hin = hbuf + (size_t)((t + 1) & 1) * NB * NH;
    ushort_t*      hout = hbuf + (size_t)(t & 1) * NB * NH;
    stepA_kernel<<<512, 256, 0, stream>>>(t, sIn, z_bf, wih, bih, bhh, whh_bf, wz_bf,
                                          hin, hout, cws, yws, qks, out);
    stepB_kernel<<<256, 256, 0, stream>>>(t, hout, wdec_bf, bdec, yws, qks);
  }
  finalC_kernel<<<256, 512, 0, stream>>>(yws, qks, out);
}